// Round 5
// baseline (2890.718 us; speedup 1.0000x reference)
//
#include <hip/hip_runtime.h>
#include <hip/hip_bf16.h>
#include <stdint.h>

// ---------------------------------------------------------------------------
// BiLSTM classifier: V=50000 E=100 H=128 B=128 T=1024 C=2.
// ALL inputs/outputs are FLOAT32 (per reference jnp.float32; round-4's
// finite-4.5e36 result proved the bf16-I/O assumption wrong).
// Internals: bf16 MFMA with one-time f32->bf16 weight conversion.
//   padw: pad w_ih_l0 f32 [512,100] -> bf16 [2][512][128]
//   cvt6: w_hh x4 and w_ih_l1 x2 f32 -> bf16
//   per chunk (TC=128 x 8): proj (bf16 MFMA GEMM; emb f32 gathered+cvt
//     inline for L0; h1cat bf16 for L1; xp -> bf16), lstm (16 persistent
//     WGs; w_hh bf16 VGPRs; h bf16 LDS; c f32 regs; HS bf16/CS f32 carry)
//   fc: finals f32 . fc_w f32 -> out f32
// Workspace: 102,301,696 B (< 134,873,088 proven available in r2-r4).
// ---------------------------------------------------------------------------

typedef unsigned short u16;
typedef short bf16x8 __attribute__((ext_vector_type(8)));
typedef unsigned short ushort8v __attribute__((ext_vector_type(8)));
typedef float f32x4 __attribute__((ext_vector_type(4)));

#define NB 128
#define NT 1024
#define NH 128
#define NM (NB * NT)   // 131072
#define TC 128         // chunk length (steps)
#define NCHUNK (NT / TC)

__device__ __forceinline__ u16 f2bf(float f) {
  union { float f; unsigned int i; } v; v.f = f;
  unsigned int i = v.i;
  return (u16)((i + 0x7FFFu + ((i >> 16) & 1u)) >> 16);  // RNE
}
__device__ __forceinline__ float bf2f(u16 u) {
  union { unsigned int i; float f; } v; v.i = ((unsigned int)u) << 16; return v.f;
}

#if __has_builtin(__builtin_amdgcn_exp2f)
__device__ __forceinline__ float fast_exp2(float x) { return __builtin_amdgcn_exp2f(x); }
#else
__device__ __forceinline__ float fast_exp2(float x) { return exp2f(x); }
#endif
#if __has_builtin(__builtin_amdgcn_rcpf)
__device__ __forceinline__ float fast_rcp(float x) { return __builtin_amdgcn_rcpf(x); }
#else
__device__ __forceinline__ float fast_rcp(float x) { return 1.0f / x; }
#endif

__device__ __forceinline__ float sigmoid_(float x) {
  x = fminf(fmaxf(x, -30.f), 30.f);
  return fast_rcp(1.0f + fast_exp2(-1.44269504f * x));
}
__device__ __forceinline__ float tanh_(float x) {
  x = fminf(fmaxf(x, -15.f), 15.f);
  return 1.0f - 2.0f * fast_rcp(1.0f + fast_exp2(2.88539008f * x));
}

// ---------------------------------------------------------------------------
// pad w_ih_l0 f32 [512,100] -> bf16 [2][512][128] (zeros in cols 100:128)
__global__ void padw_kernel(const float* __restrict__ w0, const float* __restrict__ w1,
                            u16* __restrict__ out) {
  int idx = blockIdx.x * 256 + threadIdx.x;  // 131072
  int d = idx >> 16;
  int n = (idx >> 7) & 511;
  int k = idx & 127;
  const float* w = d ? w1 : w0;
  out[idx] = (k < 100) ? f2bf(w[n * 100 + k]) : (u16)0;
}

// fused f32->bf16 convert for 6 weight arrays (grid.y selects array)
__global__ void cvt6_kernel(const float* s0, const float* s1, const float* s2,
                            const float* s3, const float* s4, const float* s5,
                            u16* d0, u16* d1, u16* d2, u16* d3, u16* d4, u16* d5,
                            int n0, int n1, int n2, int n3, int n4, int n5) {
  int y = blockIdx.y;
  const float* s; u16* d; int n;
  switch (y) {
    case 0: s = s0; d = d0; n = n0; break;
    case 1: s = s1; d = d1; n = n1; break;
    case 2: s = s2; d = d2; n = n2; break;
    case 3: s = s3; d = d3; n = n3; break;
    case 4: s = s4; d = d4; n = n4; break;
    default: s = s5; d = d5; n = n5; break;
  }
  int i = blockIdx.x * 256 + threadIdx.x;
  if (i < n) d[i] = f2bf(s[i]);
}

// ---------------------------------------------------------------------------
// projection GEMM for one chunk: xpc[dir][b][tl][n] (bf16) =
//   A[b, t(dir,c,tl), :] . W[n,:] + b_ih[n] + b_hh[n]
// GATHER: layer 0 — A-rows gathered from emb (f32, cvt inline).
// else:   layer 1 — A = h1cat bf16 [NM][256].
// grid (128 b, 4 ntile, 2 dir), block 256 (4 waves, 2x2 of 64x64).
template <int K, bool GATHER>
__global__ __launch_bounds__(256) void proj_chunk(
    const float* __restrict__ Aemb, const u16* __restrict__ Ah,
    const int* __restrict__ X,
    const u16* __restrict__ W0, const u16* __restrict__ W1,   // [512][K] bf16
    const float* __restrict__ bih0, const float* __restrict__ bhh0,
    const float* __restrict__ bih1, const float* __restrict__ bhh1,
    u16* __restrict__ XPC, int c)
{
  constexpr int BK = 64;
  constexpr int LDA = 72;  // row stride 144 B (16B multiple)
  __shared__ __align__(16) u16 As[128 * LDA];
  __shared__ __align__(16) u16 Bs[128 * LDA];
  __shared__ int toks[128];

  const int b = blockIdx.x;
  const int nt0 = blockIdx.y * 128;
  const int dir = blockIdx.z;
  const u16* W = dir ? W1 : W0;

  const int tid = threadIdx.x;
  const int lane = tid & 63, wv = tid >> 6;
  const int wr = wv >> 1, wc = wv & 1;
  const int l15 = lane & 15, q = lane >> 4;

  if (GATHER) {
    if (tid < 128) {
      int t = dir ? (NT - 1 - c * TC - tid) : (c * TC + tid);
      toks[tid] = X[b * NT + t];
    }
  }

  f32x4 acc[4][4];
#pragma unroll
  for (int a = 0; a < 4; a++)
#pragma unroll
    for (int bb = 0; bb < 4; bb++)
      acc[a][bb] = (f32x4){0.f, 0.f, 0.f, 0.f};

  const int srow = tid >> 3;        // 0..31
  const int sseg = (tid & 7) * 8;   // 0..56

  for (int k0 = 0; k0 < K; k0 += BK) {
    __syncthreads();   // also covers toks on first iteration
#pragma unroll
    for (int p = 0; p < 4; p++) {
      int row = srow + p * 32;
      if (GATHER) {
        int tok = toks[row];
        const float* er = Aemb + (size_t)tok * 100;
        int kb = k0 + sseg;
        union { ushort8v v; u16 e[8]; } tu;
        if (kb + 8 <= 100) {
          f32x4 a0 = *(const f32x4*)&er[kb];      // 16B-aligned: 400*tok + 4*kb
          f32x4 a1 = *(const f32x4*)&er[kb + 4];
#pragma unroll
          for (int j = 0; j < 4; j++) { tu.e[j] = f2bf(a0[j]); tu.e[4 + j] = f2bf(a1[j]); }
        } else {
#pragma unroll
          for (int j = 0; j < 8; j++) tu.e[j] = (kb + j < 100) ? f2bf(er[kb + j]) : (u16)0;
        }
        *(ushort8v*)&As[row * LDA + sseg] = tu.v;
      } else {
        int t = dir ? (NT - 1 - c * TC - row) : (c * TC + row);
        const u16* srcA = Ah + (size_t)(b * NT + t) * K + k0 + sseg;
        *(ushort8v*)&As[row * LDA + sseg] = *(const ushort8v*)srcA;
      }
      const u16* srcB = W + (size_t)(nt0 + row) * K + k0 + sseg;
      *(ushort8v*)&Bs[row * LDA + sseg] = *(const ushort8v*)srcB;
    }
    __syncthreads();
#pragma unroll
    for (int kk = 0; kk < BK; kk += 32) {
      bf16x8 af[4], bfr[4];
#pragma unroll
      for (int mt = 0; mt < 4; mt++)
        af[mt] = *(const bf16x8*)&As[(wr * 64 + mt * 16 + l15) * LDA + kk + q * 8];
#pragma unroll
      for (int nt = 0; nt < 4; nt++)
        bfr[nt] = *(const bf16x8*)&Bs[(wc * 64 + nt * 16 + l15) * LDA + kk + q * 8];
#pragma unroll
      for (int mt = 0; mt < 4; mt++)
#pragma unroll
        for (int nt = 0; nt < 4; nt++)
          acc[mt][nt] = __builtin_amdgcn_mfma_f32_16x16x32_bf16(af[mt], bfr[nt], acc[mt][nt], 0, 0, 0);
    }
  }

  const float* bih = dir ? bih1 : bih0;
  const float* bhh = dir ? bhh1 : bhh0;
  u16* xo = XPC + ((size_t)(dir * 128 + b) * TC) * 512;
#pragma unroll
  for (int nt = 0; nt < 4; nt++) {
    int n = nt0 + wc * 64 + nt * 16 + l15;
    float bias = bih[n] + bhh[n];
#pragma unroll
    for (int mt = 0; mt < 4; mt++) {
      int rbase = wr * 64 + mt * 16 + q * 4;   // = tl (step-local index)
#pragma unroll
      for (int r = 0; r < 4; r++)
        xo[(size_t)(rbase + r) * 512 + n] = f2bf(acc[mt][nt][r] + bias);
    }
  }
}

// ---------------------------------------------------------------------------
// recurrent LSTM, one chunk of TC steps. grid (8 batch-chunks, 2 dirs),
// block 512 (8 waves). Wave w owns within-gate cols [16w,16w+16): MFMA
// C-tile gi -> gate gi col 16w+l15, so i/f/g/o for one h-element land in one
// lane; c f32 in VGPRs. h bf16 in LDS; w_hh resident bf16 VGPRs; xp bf16
// from global with 1-step register prefetch.
template <int LAYER>
__global__ __launch_bounds__(512) void lstm_chunk(
    const u16* __restrict__ XPC,         // [2][128][TC][512] bf16
    const u16* __restrict__ WHH0, const u16* __restrict__ WHH1,  // [512][128] bf16
    u16* __restrict__ OUT,               // layer0: h1cat bf16 [NM][256]
    float* __restrict__ FINALS,          // layer1: [128][256] f32
    u16* __restrict__ HS, float* __restrict__ CS,  // [2][128][128] state
    int c)
{
  const int wg = blockIdx.x, dir = blockIdx.y;
  const int tid = threadIdx.x;
  const int lane = tid & 63, wv = tid >> 6;
  const int l15 = lane & 15, q = lane >> 4;
  const int hc = 16 * wv + l15;

  const u16* Wp = dir ? WHH1 : WHH0;
  bf16x8 wf[4][4];
#pragma unroll
  for (int gi = 0; gi < 4; gi++)
#pragma unroll
    for (int kt = 0; kt < 4; kt++)
      wf[gi][kt] = *(const bf16x8*)&Wp[(gi * 128 + hc) * 128 + kt * 32 + q * 8];

  __shared__ __align__(16) u16 hb[2][16 * 136];  // row stride 136

  float cst[4];
  if (c == 0) {
    for (int i = tid; i < 16 * 136; i += 512) hb[0][i] = 0;
#pragma unroll
    for (int r = 0; r < 4; r++) cst[r] = 0.f;
  } else {
#pragma unroll
    for (int r = 0; r < 4; r++) {
      int row = q * 4 + r;
      int g = (dir * 128 + wg * 16 + row) * 128 + hc;
      hb[0][row * 136 + hc] = HS[g];
      cst[r] = CS[g];
    }
  }

  const u16* xpp = XPC + ((size_t)(dir * 128 + wg * 16) * TC) * 512;
  float xpv[16];
#pragma unroll
  for (int gi = 0; gi < 4; gi++)
#pragma unroll
    for (int r = 0; r < 4; r++)
      xpv[gi * 4 + r] = bf2f(xpp[((size_t)(q * 4 + r) * TC) * 512 + gi * 128 + hc]);

  __syncthreads();

  int p = 0;
  for (int sl = 0; sl < TC; sl++) {
    bf16x8 ah[4];
#pragma unroll
    for (int kt = 0; kt < 4; kt++)
      ah[kt] = *(const bf16x8*)&hb[p][l15 * 136 + kt * 32 + q * 8];

    // prefetch next step's xp (clamped index: harmless re-read at last step)
    const int sln = (sl + 1 < TC) ? sl + 1 : sl;
    float xnv[16];
#pragma unroll
    for (int gi = 0; gi < 4; gi++)
#pragma unroll
      for (int r = 0; r < 4; r++)
        xnv[gi * 4 + r] = bf2f(xpp[((size_t)(q * 4 + r) * TC + sln) * 512 + gi * 128 + hc]);

    f32x4 acc[4];
#pragma unroll
    for (int gi = 0; gi < 4; gi++)
#pragma unroll
      for (int r = 0; r < 4; r++)
        acc[gi][r] = xpv[gi * 4 + r];
#pragma unroll
    for (int gi = 0; gi < 4; gi++)
#pragma unroll
      for (int kt = 0; kt < 4; kt++)
        acc[gi] = __builtin_amdgcn_mfma_f32_16x16x32_bf16(ah[kt], wf[gi][kt], acc[gi], 0, 0, 0);

    const int t_eff = dir ? (NT - 1 - (c * TC + sl)) : (c * TC + sl);
#pragma unroll
    for (int r = 0; r < 4; r++) {
      float iv = sigmoid_(acc[0][r]);
      float fv = sigmoid_(acc[1][r]);
      float gv = tanh_(acc[2][r]);
      float ov = sigmoid_(acc[3][r]);
      cst[r] = fv * cst[r] + iv * gv;
      float hv = ov * tanh_(cst[r]);
      u16 hbv = f2bf(hv);
      int row = q * 4 + r;
      hb[p ^ 1][row * 136 + hc] = hbv;
      if (LAYER == 0)
        OUT[((size_t)(wg * 16 + row) * NT + t_eff) * 256 + dir * 128 + hc] = hbv;
      if (sl == TC - 1) {
        int g = (dir * 128 + wg * 16 + row) * 128 + hc;
        HS[g] = hbv;
        CS[g] = cst[r];
        if (LAYER == 1 && c == NCHUNK - 1)
          FINALS[(wg * 16 + row) * 256 + dir * 128 + hc] = hv;
      }
    }
    __syncthreads();
    p ^= 1;
#pragma unroll
    for (int i = 0; i < 16; i++) xpv[i] = xnv[i];
  }
}

// ---------------------------------------------------------------------------
// fc: out[b][c] = finals[b][:] . fc_w[c][:] + fc_b[c]  (all f32)
__global__ void fc_kernel(const float* __restrict__ finals, const float* __restrict__ fcw,
                          const float* __restrict__ fcb, float* __restrict__ out) {
  int tid = threadIdx.x;  // 256 = 128 b x 2 c
  int b = tid >> 1, cc = tid & 1;
  float s = fcb[cc];
  for (int k = 0; k < 256; k++) s += finals[b * 256 + k] * fcw[cc * 256 + k];
  out[b * 2 + cc] = s;
}

// ---------------------------------------------------------------------------
extern "C" void kernel_launch(void* const* d_in, const int* in_sizes, int n_in,
                              void* d_out, int out_size, void* d_ws, size_t ws_size,
                              hipStream_t stream) {
  const int*   x        = (const int*)d_in[0];
  const float* emb      = (const float*)d_in[1];
  const float* w_ih_l0  = (const float*)d_in[2];
  const float* w_hh_l0  = (const float*)d_in[3];
  const float* b_ih_l0  = (const float*)d_in[4];
  const float* b_hh_l0  = (const float*)d_in[5];
  const float* w_ih_l0r = (const float*)d_in[6];
  const float* w_hh_l0r = (const float*)d_in[7];
  const float* b_ih_l0r = (const float*)d_in[8];
  const float* b_hh_l0r = (const float*)d_in[9];
  const float* w_ih_l1  = (const float*)d_in[10];
  const float* w_hh_l1  = (const float*)d_in[11];
  const float* b_ih_l1  = (const float*)d_in[12];
  const float* b_hh_l1  = (const float*)d_in[13];
  const float* w_ih_l1r = (const float*)d_in[14];
  const float* w_hh_l1r = (const float*)d_in[15];
  const float* b_ih_l1r = (const float*)d_in[16];
  const float* b_hh_l1r = (const float*)d_in[17];
  const float* fc_w     = (const float*)d_in[18];
  const float* fc_b     = (const float*)d_in[19];
  float* out = (float*)d_out;

  // workspace layout — total 102,301,696 B (< 134,873,088 proven in r2-r4)
  char* ws = (char*)d_ws;
  size_t off = 0;
  u16*   h1cat = (u16*)(ws + off);   off += 67108864;  // [NM][256] bf16
  u16*   xpc   = (u16*)(ws + off);   off += 33554432;  // [2][128][TC][512] bf16
  u16*   w0pad = (u16*)(ws + off);   off += 262144;    // [2][512][128] bf16
  u16*   wih1b = (u16*)(ws + off);   off += 524288;    // [2][512][256] bf16
  u16*   whhb  = (u16*)(ws + off);   off += 524288;    // [4][512][128] bf16
  u16*   hs    = (u16*)(ws + off);   off += 65536;     // [2][128][128] bf16
  float* cs    = (float*)(ws + off); off += 131072;    // [2][128][128] f32
  float* fin   = (float*)(ws + off); off += 131072;    // [128][256] f32
  if (ws_size < off) return;  // constant across calls -> same work every call

  hipLaunchKernelGGL(padw_kernel, dim3(512), dim3(256), 0, stream,
                     w_ih_l0, w_ih_l0r, w0pad);
  hipLaunchKernelGGL(cvt6_kernel, dim3(512, 6), dim3(256), 0, stream,
                     w_hh_l0, w_hh_l0r, w_hh_l1, w_hh_l1r, w_ih_l1, w_ih_l1r,
                     whhb, whhb + 65536, whhb + 131072, whhb + 196608,
                     wih1b, wih1b + 131072,
                     65536, 65536, 65536, 65536, 131072, 131072);

  for (int c = 0; c < NCHUNK; c++) {
    hipLaunchKernelGGL((proj_chunk<128, true>), dim3(128, 4, 2), dim3(256), 0, stream,
                       emb, (const u16*)nullptr, x, w0pad, w0pad + 65536,
                       b_ih_l0, b_hh_l0, b_ih_l0r, b_hh_l0r, xpc, c);
    hipLaunchKernelGGL((lstm_chunk<0>), dim3(8, 2), dim3(512), 0, stream,
                       xpc, whhb, whhb + 65536, h1cat, fin, hs, cs, c);
  }
  for (int c = 0; c < NCHUNK; c++) {
    hipLaunchKernelGGL((proj_chunk<256, false>), dim3(128, 4, 2), dim3(256), 0, stream,
                       (const float*)nullptr, h1cat, (const int*)nullptr,
                       wih1b, wih1b + 131072,
                       b_ih_l1, b_hh_l1, b_ih_l1r, b_hh_l1r, xpc, c);
    hipLaunchKernelGGL((lstm_chunk<1>), dim3(8, 2), dim3(512), 0, stream,
                       xpc, whhb + 131072, whhb + 196608, h1cat, fin, hs, cs, c);
  }
  hipLaunchKernelGGL(fc_kernel, dim3(1), dim3(256), 0, stream, fin, fc_w, fc_b, out);
}